// Round 1
// baseline (562.063 us; speedup 1.0000x reference)
//
#include <hip/hip_runtime.h>
#include <hip/hip_bf16.h>

#define HEADS 12
#define HSIZE 64
#define BATCH 32
#define SEQ 512
#define DIM 768
#define NOUT 1536    // HEADS*HSIZE*2
#define MROWS 16384  // BATCH*SEQ
#define NEGV 1e12f

typedef __bf16 bf16x8 __attribute__((ext_vector_type(8)));
typedef float f32x4 __attribute__((ext_vector_type(4)));

__device__ __forceinline__ void async16(const void* g, void* l) {
  __builtin_amdgcn_global_load_lds(
      (const __attribute__((address_space(1))) void*)g,
      (__attribute__((address_space(3))) void*)l, 16, 0, 0);
}

__device__ __forceinline__ unsigned short f2b(float f) {
  union { __hip_bfloat16 h; unsigned short u; } cv;
  cv.h = __float2bfloat16(f);
  return cv.u;
}

// ---------------- kernel 1: RoPE sin/cos table (SEQ x 32) ----------------
__global__ void rope_table(float* __restrict__ sin_t, float* __restrict__ cos_t) {
  int idx = blockIdx.x * 256 + threadIdx.x;
  if (idx < SEQ * 32) {
    int pos = idx >> 5;
    int i = idx & 31;
    float freq = powf(10000.0f, -2.0f * (float)i / 64.0f);
    float ang = (float)pos * freq;
    sin_t[idx] = sinf(ang);
    cos_t[idx] = cosf(ang);
  }
}

// ---------------- kernel 2: x fp32 -> bf16, vectorized ----------------
__global__ void convert_x(const float* __restrict__ x, unsigned short* __restrict__ xb) {
  int idx = blockIdx.x * 256 + threadIdx.x;  // each handles 4 floats
  float4 v = ((const float4*)x)[idx];
  ushort4 o;
  o.x = f2b(v.x); o.y = f2b(v.y); o.z = f2b(v.z); o.w = f2b(v.w);
  ((ushort4*)xb)[idx] = o;
}

// ------------- kernel 3: W (DIM x NOUT) -> Wt (NOUT x DIM) bf16 -------------
__global__ void transpose_w(const float* __restrict__ W, unsigned short* __restrict__ Wt) {
  __shared__ unsigned short tile[32][33];
  int n0 = blockIdx.x * 32;  // 48 tiles
  int k0 = blockIdx.y * 32;  // 24 tiles
  int tx = threadIdx.x & 31, ty = threadIdx.x >> 5;  // 32 x 8
#pragma unroll
  for (int j = 0; j < 32; j += 8) {
    tile[ty + j][tx] = f2b(W[(size_t)(k0 + ty + j) * NOUT + n0 + tx]);
  }
  __syncthreads();
#pragma unroll
  for (int j = 0; j < 32; j += 8) {
    Wt[(size_t)(n0 + ty + j) * DIM + k0 + tx] = tile[tx][ty + j];
  }
}

// ---- kernel 4: C = xb @ Wt^T (+bias, RoPE) -> q_ws/k_ws (B,H,L,64) bf16 ----
// 128x128 tile, BK=32, 4 waves (2x2), each wave 64x64 of 16x16x32 MFMA.
__global__ __launch_bounds__(256) void gemm_rope(
    const unsigned short* __restrict__ xb, const unsigned short* __restrict__ wt,
    const float* __restrict__ bias, const float* __restrict__ sin_t,
    const float* __restrict__ cos_t, unsigned short* __restrict__ q_ws,
    unsigned short* __restrict__ k_ws) {
  __shared__ unsigned short As[128 * 32];
  __shared__ unsigned short Bs[128 * 32];
  const int tid = threadIdx.x;
  const int bx = blockIdx.x;
  const int tn = (bx % (NOUT / 128)) * 128;
  const int tm = (bx / (NOUT / 128)) * 128;
  const int wid = tid >> 6, lane = tid & 63;
  const int wr = (wid >> 1) * 64, wc = (wid & 1) * 64;
  const int lrow = lane & 15, lk = (lane >> 4) * 8;

  // staging: 256 threads x 16B = 4KB per issue; tile = 8KB -> 2 issues each
  const int sr = tid >> 2;          // 0..63
  const int sc = (tid & 3) * 8;     // 0,8,16,24
  const unsigned short* a_src0 = xb + (size_t)(tm + sr) * DIM + sc;
  const unsigned short* a_src1 = xb + (size_t)(tm + 64 + sr) * DIM + sc;
  const unsigned short* b_src0 = wt + (size_t)(tn + sr) * DIM + sc;
  const unsigned short* b_src1 = wt + (size_t)(tn + 64 + sr) * DIM + sc;
  unsigned short* a_dst0 = &As[tid * 8];
  unsigned short* a_dst1 = &As[2048 + tid * 8];
  unsigned short* b_dst0 = &Bs[tid * 8];
  unsigned short* b_dst1 = &Bs[2048 + tid * 8];

  f32x4 acc[4][4] = {};
  for (int k0 = 0; k0 < DIM; k0 += 32) {
    async16(a_src0 + k0, a_dst0);
    async16(a_src1 + k0, a_dst1);
    async16(b_src0 + k0, b_dst0);
    async16(b_src1 + k0, b_dst1);
    __syncthreads();  // compiler emits vmcnt(0) drain before barrier
    bf16x8 af[4], bfr[4];
#pragma unroll
    for (int i = 0; i < 4; ++i) {
      af[i]  = *(const bf16x8*)&As[(wr + i * 16 + lrow) * 32 + lk];
      bfr[i] = *(const bf16x8*)&Bs[(wc + i * 16 + lrow) * 32 + lk];
    }
#pragma unroll
    for (int mi = 0; mi < 4; ++mi)
#pragma unroll
      for (int ni = 0; ni < 4; ++ni)
        acc[mi][ni] = __builtin_amdgcn_mfma_f32_16x16x32_bf16(
            af[mi], bfr[ni], acc[mi][ni], 0, 0, 0);
    __syncthreads();
  }

  // epilogue: bias + RoPE + scatter to (B,H,L,64) bf16 panels
#pragma unroll
  for (int ni = 0; ni < 4; ++ni) {
    const int colb = tn + wc + ni * 16 + lrow;       // 0..1535
    const float bia = bias[colb];
    const int ii = (colb & 63) >> 1;                 // rope pair index 0..31
    const int head = colb >> 7;
    const int is_k = (colb >> 6) & 1;
    const int d = colb & 63;
    unsigned short* dst = is_k ? k_ws : q_ws;
#pragma unroll
    for (int mi = 0; mi < 4; ++mi) {
#pragma unroll
      for (int r = 0; r < 4; ++r) {
        const int row = tm + wr + mi * 16 + (lane >> 4) * 4 + r;  // 0..16383
        float v = acc[mi][ni][r] + bia;
        float p = __shfl_xor(v, 1, 64);  // partner column (col^1)
        const int pos = row & (SEQ - 1);
        const float sv = sin_t[pos * 32 + ii];
        const float cv = cos_t[pos * 32 + ii];
        float o = (colb & 1) ? fmaf(v, cv, p * sv) : fmaf(v, cv, -p * sv);
        const int bidx = row >> 9;
        dst[(((size_t)((bidx * HEADS + head) * SEQ + pos)) << 6) + d] = f2b(o);
      }
    }
  }
}

// -------- kernel 5: logits = q @ k^T per (b,h); mask + tril + scale --------
// grid = B*H*16 blocks; each block one 128x128 tile of the 512x512 matrix.
__global__ __launch_bounds__(256) void qk_kernel(
    const unsigned short* __restrict__ q_ws, const unsigned short* __restrict__ k_ws,
    const float* __restrict__ mask, float* __restrict__ out) {
  const int bx = blockIdx.x;
  const int bh = bx >> 4;
  const int t = bx & 15;
  const int tmm = (t >> 2) * 128, tnn = (t & 3) * 128;
  const int bidx = bh / HEADS;
  const int tid = threadIdx.x, wid = tid >> 6, lane = tid & 63;
  const int wr = (wid >> 1) * 64, wc = (wid & 1) * 64;
  const int lrow = lane & 15, lk = (lane >> 4) * 8;
  const unsigned short* Q = q_ws + ((size_t)bh << 15);  // 512*64
  const unsigned short* K = k_ws + ((size_t)bh << 15);

  bf16x8 qa[4][2], kb[4][2];
#pragma unroll
  for (int i = 0; i < 4; ++i) {
#pragma unroll
    for (int ks = 0; ks < 2; ++ks) {
      qa[i][ks] = *(const bf16x8*)&Q[(size_t)(tmm + wr + i * 16 + lrow) * 64 + ks * 32 + lk];
      kb[i][ks] = *(const bf16x8*)&K[(size_t)(tnn + wc + i * 16 + lrow) * 64 + ks * 32 + lk];
    }
  }
  f32x4 acc[4][4] = {};
#pragma unroll
  for (int mi = 0; mi < 4; ++mi)
#pragma unroll
    for (int ni = 0; ni < 4; ++ni) {
      acc[mi][ni] = __builtin_amdgcn_mfma_f32_16x16x32_bf16(qa[mi][0], kb[ni][0], acc[mi][ni], 0, 0, 0);
      acc[mi][ni] = __builtin_amdgcn_mfma_f32_16x16x32_bf16(qa[mi][1], kb[ni][1], acc[mi][ni], 0, 0, 0);
    }

  float* obase = out + ((size_t)bh << 18);  // 512*512
  const float* mrow = mask + (size_t)bidx * SEQ;
#pragma unroll
  for (int mi = 0; mi < 4; ++mi) {
#pragma unroll
    for (int ni = 0; ni < 4; ++ni) {
      const int n = tnn + wc + ni * 16 + lrow;
      const float m3 = mrow[n];
#pragma unroll
      for (int r = 0; r < 4; ++r) {
        const int m = tmm + wr + mi * 16 + (lane >> 4) * 4 + r;
        const float m2 = mrow[m];
        float v = acc[mi][ni][r];
        v = v * m2 + (1.0f - m2) * (-NEGV);
        v = v * m3 + (1.0f - m3) * (-NEGV);
        if (m > n) v -= NEGV;
        obase[(size_t)m * 512 + n] = v * 0.125f;
      }
    }
  }
}

extern "C" void kernel_launch(void* const* d_in, const int* in_sizes, int n_in,
                              void* d_out, int out_size, void* d_ws, size_t ws_size,
                              hipStream_t stream) {
  const float* x = (const float*)d_in[0];
  const float* mask = (const float*)d_in[1];
  const float* W = (const float*)d_in[2];
  const float* b = (const float*)d_in[3];
  float* out = (float*)d_out;

  char* ws = (char*)d_ws;
  // layout (256B aligned)
  float* sin_t = (float*)(ws + 0);                       //  64 KB
  float* cos_t = (float*)(ws + 65536);                   //  64 KB
  unsigned short* xb  = (unsigned short*)(ws + 131072);  //  24 MB (16384x768)
  unsigned short* wt  = (unsigned short*)(ws + 25296896); // 2.25 MB (1536x768)
  unsigned short* q_ws = (unsigned short*)(ws + 27656192); // 24 MB (32,12,512,64)
  unsigned short* k_ws = (unsigned short*)(ws + 52822016); // 24 MB

  rope_table<<<dim3(64), dim3(256), 0, stream>>>(sin_t, cos_t);
  convert_x<<<dim3(MROWS * DIM / 4 / 256), dim3(256), 0, stream>>>(x, xb);
  transpose_w<<<dim3(NOUT / 32, DIM / 32), dim3(256), 0, stream>>>(W, wt);
  gemm_rope<<<dim3((MROWS / 128) * (NOUT / 128)), dim3(256), 0, stream>>>(
      xb, wt, b, sin_t, cos_t, q_ws, k_ws);
  qk_kernel<<<dim3(BATCH * HEADS * 16), dim3(256), 0, stream>>>(q_ws, k_ws, mask, out);
}

// Round 5
// 558.145 us; speedup vs baseline: 1.0070x; 1.0070x over previous
//
#include <hip/hip_runtime.h>
#include <hip/hip_bf16.h>

#define HEADS 12
#define HSIZE 64
#define BATCH 32
#define SEQ 512
#define DIM 768
#define NOUT 1536    // HEADS*HSIZE*2
#define MROWS 16384  // BATCH*SEQ
#define NEGV 1e12f

typedef __bf16 bf16x8 __attribute__((ext_vector_type(8)));
typedef float f32x4 __attribute__((ext_vector_type(4)));

__device__ __forceinline__ void async16(const void* g, void* l) {
  __builtin_amdgcn_global_load_lds(
      (const __attribute__((address_space(1))) void*)g,
      (__attribute__((address_space(3))) void*)l, 16, 0, 0);
}

__device__ __forceinline__ unsigned short f2b(float f) {
  union { __hip_bfloat16 h; unsigned short u; } cv;
  cv.h = __float2bfloat16(f);
  return cv.u;
}

// ---------------- kernel 1: RoPE sin/cos table (SEQ x 32) ----------------
__global__ void rope_table(float* __restrict__ sin_t, float* __restrict__ cos_t) {
  int idx = blockIdx.x * 256 + threadIdx.x;
  if (idx < SEQ * 32) {
    int pos = idx >> 5;
    int i = idx & 31;
    float freq = powf(10000.0f, -2.0f * (float)i / 64.0f);
    float ang = (float)pos * freq;
    sin_t[idx] = sinf(ang);
    cos_t[idx] = cosf(ang);
  }
}

// ---------------- kernel 2: x fp32 -> bf16, vectorized ----------------
__global__ void convert_x(const float* __restrict__ x, unsigned short* __restrict__ xb) {
  int idx = blockIdx.x * 256 + threadIdx.x;  // each handles 4 floats
  float4 v = ((const float4*)x)[idx];
  ushort4 o;
  o.x = f2b(v.x); o.y = f2b(v.y); o.z = f2b(v.z); o.w = f2b(v.w);
  ((ushort4*)xb)[idx] = o;
}

// ------------- kernel 3: W (DIM x NOUT) -> Wt (NOUT x DIM) bf16 -------------
__global__ void transpose_w(const float* __restrict__ W, unsigned short* __restrict__ Wt) {
  __shared__ unsigned short tile[32][33];
  int n0 = blockIdx.x * 32;
  int k0 = blockIdx.y * 32;
  int tx = threadIdx.x & 31, ty = threadIdx.x >> 5;  // 32 x 8
#pragma unroll
  for (int j = 0; j < 32; j += 8) {
    tile[ty + j][tx] = f2b(W[(size_t)(k0 + ty + j) * NOUT + n0 + tx]);
  }
  __syncthreads();
#pragma unroll
  for (int j = 0; j < 32; j += 8) {
    Wt[(size_t)(n0 + ty + j) * DIM + k0 + tx] = tile[tx][ty + j];
  }
}

// ---- kernel 4: proj = xb @ Wt^T (+bias, RoPE) -> q_ws/k_ws (B,H,L,64) bf16 ----
// 128x128 tile, BK=32, 4 waves (2x2), m97 structure.
// OPERAND SWAP: acc = mfma(n_frag, m_frag) so D rows = n (reg-consecutive d),
// D cols = m (lane). RoPE pairs land in-lane; stores are ushort4.
__global__ __launch_bounds__(256) void gemm_rope(
    const unsigned short* __restrict__ xb, const unsigned short* __restrict__ wt,
    const float* __restrict__ bias, const float* __restrict__ sin_t,
    const float* __restrict__ cos_t, unsigned short* __restrict__ q_ws,
    unsigned short* __restrict__ k_ws) {
  __shared__ unsigned short As[128 * 32];  // xb rows (m)
  __shared__ unsigned short Bs[128 * 32];  // wt rows (n)
  const int tid = threadIdx.x;
  const int bx = blockIdx.x;
  const int tn = (bx % (NOUT / 128)) * 128;
  const int tm = (bx / (NOUT / 128)) * 128;
  const int wid = tid >> 6, lane = tid & 63;
  const int wm = (wid >> 1) * 64, wn = (wid & 1) * 64;
  const int lrow = lane & 15, lk = (lane >> 4) * 8;

  const int sr = tid >> 2;
  const int sc = (tid & 3) * 8;
  const unsigned short* a_src0 = xb + (size_t)(tm + sr) * DIM + sc;
  const unsigned short* a_src1 = xb + (size_t)(tm + 64 + sr) * DIM + sc;
  const unsigned short* b_src0 = wt + (size_t)(tn + sr) * DIM + sc;
  const unsigned short* b_src1 = wt + (size_t)(tn + 64 + sr) * DIM + sc;
  unsigned short* a_dst0 = &As[tid * 8];
  unsigned short* a_dst1 = &As[2048 + tid * 8];
  unsigned short* b_dst0 = &Bs[tid * 8];
  unsigned short* b_dst1 = &Bs[2048 + tid * 8];

  f32x4 acc[4][4] = {};  // [ai = n-frag][bi = m-frag]
  for (int k0 = 0; k0 < DIM; k0 += 32) {
    async16(a_src0 + k0, a_dst0);
    async16(a_src1 + k0, a_dst1);
    async16(b_src0 + k0, b_dst0);
    async16(b_src1 + k0, b_dst1);
    __syncthreads();
    bf16x8 nf[4], mf[4];
#pragma unroll
    for (int i = 0; i < 4; ++i) {
      nf[i] = *(const bf16x8*)&Bs[(wn + i * 16 + lrow) * 32 + lk];
      mf[i] = *(const bf16x8*)&As[(wm + i * 16 + lrow) * 32 + lk];
    }
#pragma unroll
    for (int ai = 0; ai < 4; ++ai)
#pragma unroll
      for (int bi = 0; bi < 4; ++bi)
        acc[ai][bi] = __builtin_amdgcn_mfma_f32_16x16x32_bf16(
            nf[ai], mf[bi], acc[ai][bi], 0, 0, 0);
    __syncthreads();
  }

  // epilogue: bias + RoPE (in-lane pairs) + ushort4 stores to (B,H,L,64)
#pragma unroll
  for (int ai = 0; ai < 4; ++ai) {
    const int nb = tn + wn + ai * 16 + (lane >> 4) * 4;  // 4-aligned col base
    const int head = nb >> 7;
    const int is_k = (nb >> 6) & 1;
    const int d0 = nb & 63;
    const float4 b4 = *(const float4*)&bias[nb];
    unsigned short* dst = is_k ? k_ws : q_ws;
#pragma unroll
    for (int bi = 0; bi < 4; ++bi) {
      const int row = tm + wm + bi * 16 + lrow;  // 0..16383
      const int bidx = row >> 9;
      const int pos = row & (SEQ - 1);
      const float2 s01 = *(const float2*)&sin_t[pos * 32 + (d0 >> 1)];
      const float2 c01 = *(const float2*)&cos_t[pos * 32 + (d0 >> 1)];
      const float v0 = acc[ai][bi][0] + b4.x;
      const float v1 = acc[ai][bi][1] + b4.y;
      const float v2 = acc[ai][bi][2] + b4.z;
      const float v3 = acc[ai][bi][3] + b4.w;
      ushort4 pk;
      pk.x = f2b(fmaf(v0, c01.x, -v1 * s01.x));
      pk.y = f2b(fmaf(v1, c01.x,  v0 * s01.x));
      pk.z = f2b(fmaf(v2, c01.y, -v3 * s01.y));
      pk.w = f2b(fmaf(v3, c01.y,  v2 * s01.y));
      *(ushort4*)&dst[(((size_t)((bidx * HEADS + head) * SEQ + pos)) << 6) + d0] = pk;
    }
  }
}

// -------- kernel 5: logits = q @ k^T per (b,h); mask + tril + scale --------
// OPERAND SWAP: acc = mfma(k_frag, q_frag) -> D rows = n (reg-consecutive),
// D cols = m (lane) -> f32x4 stores along n.
__global__ __launch_bounds__(256) void qk_kernel(
    const unsigned short* __restrict__ q_ws, const unsigned short* __restrict__ k_ws,
    const float* __restrict__ mask, float* __restrict__ out) {
  const int bx = blockIdx.x;
  const int bh = bx >> 4;
  const int t = bx & 15;
  const int tmm = (t >> 2) * 128, tnn = (t & 3) * 128;
  const int bidx = bh / HEADS;
  const int tid = threadIdx.x, wid = tid >> 6, lane = tid & 63;
  const int wm = (wid >> 1) * 64, wn = (wid & 1) * 64;
  const int lrow = lane & 15, lk = (lane >> 4) * 8;
  const unsigned short* Q = q_ws + ((size_t)bh << 15);  // 512*64
  const unsigned short* K = k_ws + ((size_t)bh << 15);

  bf16x8 kf[4][2], qf[4][2];
#pragma unroll
  for (int i = 0; i < 4; ++i) {
#pragma unroll
    for (int ks = 0; ks < 2; ++ks) {
      kf[i][ks] = *(const bf16x8*)&K[(size_t)(tnn + wn + i * 16 + lrow) * 64 + ks * 32 + lk];
      qf[i][ks] = *(const bf16x8*)&Q[(size_t)(tmm + wm + i * 16 + lrow) * 64 + ks * 32 + lk];
    }
  }
  f32x4 acc[4][4] = {};  // [ai = n][bi = m]
#pragma unroll
  for (int ai = 0; ai < 4; ++ai)
#pragma unroll
    for (int bi = 0; bi < 4; ++bi) {
      acc[ai][bi] = __builtin_amdgcn_mfma_f32_16x16x32_bf16(kf[ai][0], qf[bi][0], acc[ai][bi], 0, 0, 0);
      acc[ai][bi] = __builtin_amdgcn_mfma_f32_16x16x32_bf16(kf[ai][1], qf[bi][1], acc[ai][bi], 0, 0, 0);
    }

  float* obase = out + ((size_t)bh << 18);  // 512*512
  const float* mrow = mask + (size_t)bidx * SEQ;
#pragma unroll
  for (int ai = 0; ai < 4; ++ai) {
    const int nb = tnn + wn + ai * 16 + (lane >> 4) * 4;  // 4-aligned n base
    const float4 m3 = *(const float4*)&mrow[nb];
    const float m3p[4] = {m3.x, m3.y, m3.z, m3.w};
#pragma unroll
    for (int bi = 0; bi < 4; ++bi) {
      const int m = tmm + wm + bi * 16 + lrow;
      const float m2 = mrow[m];
      f32x4 o;
#pragma unroll
      for (int r = 0; r < 4; ++r) {
        float v = acc[ai][bi][r];
        v = v * m2 + (1.0f - m2) * (-NEGV);
        v = v * m3p[r] + (1.0f - m3p[r]) * (-NEGV);
        if (m > nb + r) v -= NEGV;
        o[r] = v * 0.125f;
      }
      __builtin_nontemporal_store(o, (f32x4*)&obase[(size_t)m * 512 + nb]);
    }
  }
}

extern "C" void kernel_launch(void* const* d_in, const int* in_sizes, int n_in,
                              void* d_out, int out_size, void* d_ws, size_t ws_size,
                              hipStream_t stream) {
  const float* x = (const float*)d_in[0];
  const float* mask = (const float*)d_in[1];
  const float* W = (const float*)d_in[2];
  const float* b = (const float*)d_in[3];
  float* out = (float*)d_out;

  char* ws = (char*)d_ws;
  float* sin_t = (float*)(ws + 0);                        //  64 KB
  float* cos_t = (float*)(ws + 65536);                    //  64 KB
  unsigned short* xb  = (unsigned short*)(ws + 131072);   //  24 MB
  unsigned short* wt  = (unsigned short*)(ws + 25296896); //  2.25 MB
  unsigned short* q_ws = (unsigned short*)(ws + 27656192); // 24 MB
  unsigned short* k_ws = (unsigned short*)(ws + 52822016); // 24 MB

  rope_table<<<dim3(64), dim3(256), 0, stream>>>(sin_t, cos_t);
  convert_x<<<dim3(MROWS * DIM / 4 / 256), dim3(256), 0, stream>>>(x, xb);
  transpose_w<<<dim3(NOUT / 32, DIM / 32), dim3(256), 0, stream>>>(W, wt);
  gemm_rope<<<dim3((MROWS / 128) * (NOUT / 128)), dim3(256), 0, stream>>>(
      xb, wt, b, sin_t, cos_t, q_ws, k_ws);
  qk_kernel<<<dim3(BATCH * HEADS * 16), dim3(256), 0, stream>>>(q_ws, k_ws, mask, out);
}

// Round 7
// 529.671 us; speedup vs baseline: 1.0612x; 1.0538x over previous
//
#include <hip/hip_runtime.h>
#include <hip/hip_bf16.h>

#define HEADS 12
#define HSIZE 64
#define BATCH 32
#define SEQ 512
#define DIM 768
#define NOUT 1536    // HEADS*HSIZE*2
#define MROWS 16384  // BATCH*SEQ
#define NEGV 1e12f

typedef __bf16 bf16x8 __attribute__((ext_vector_type(8)));
typedef float f32x4 __attribute__((ext_vector_type(4)));
typedef unsigned short u16x8 __attribute__((ext_vector_type(8)));
typedef unsigned short u16x4 __attribute__((ext_vector_type(4)));

__device__ __forceinline__ void async16(const void* g, void* l) {
  __builtin_amdgcn_global_load_lds(
      (const __attribute__((address_space(1))) void*)g,
      (__attribute__((address_space(3))) void*)l, 16, 0, 0);
}

__device__ __forceinline__ unsigned short f2b(float f) {
  union { __hip_bfloat16 h; unsigned short u; } cv;
  cv.h = __float2bfloat16(f);
  return cv.u;
}

// ---------------- kernel 1: RoPE sin/cos table (SEQ x 32) ----------------
__global__ void rope_table(float* __restrict__ sin_t, float* __restrict__ cos_t) {
  int idx = blockIdx.x * 256 + threadIdx.x;
  if (idx < SEQ * 32) {
    int pos = idx >> 5;
    int i = idx & 31;
    float freq = powf(10000.0f, -2.0f * (float)i / 64.0f);
    float ang = (float)pos * freq;
    sin_t[idx] = sinf(ang);
    cos_t[idx] = cosf(ang);
  }
}

// ---------------- kernel 2: x fp32 -> bf16, vectorized ----------------
__global__ void convert_x(const float* __restrict__ x, unsigned short* __restrict__ xb) {
  int idx = blockIdx.x * 256 + threadIdx.x;  // each handles 4 floats
  float4 v = ((const float4*)x)[idx];
  ushort4 o;
  o.x = f2b(v.x); o.y = f2b(v.y); o.z = f2b(v.z); o.w = f2b(v.w);
  ((ushort4*)xb)[idx] = o;
}

// ------------- kernel 3: W (DIM x NOUT) -> Wt (NOUT x DIM) bf16 -------------
__global__ void transpose_w(const float* __restrict__ W, unsigned short* __restrict__ Wt) {
  __shared__ unsigned short tile[32][33];
  int n0 = blockIdx.x * 32;
  int k0 = blockIdx.y * 32;
  int tx = threadIdx.x & 31, ty = threadIdx.x >> 5;  // 32 x 8
#pragma unroll
  for (int j = 0; j < 32; j += 8) {
    tile[ty + j][tx] = f2b(W[(size_t)(k0 + ty + j) * NOUT + n0 + tx]);
  }
  __syncthreads();
#pragma unroll
  for (int j = 0; j < 32; j += 8) {
    Wt[(size_t)(n0 + ty + j) * DIM + k0 + tx] = tile[tx][ty + j];
  }
}

// ---- kernel 4: proj = xb @ Wt^T (+bias, RoPE) -> q_ws/k_ws (B,H,L,64) bf16 ----
// 128x128 tile, BK=32, 4 waves (2x2), m97 structure, operand-swapped MFMA
// (D rows = n so RoPE pairs are in-lane). LDS-staged epilogue -> wave
// stores are 1KB contiguous (q rows are adjacent in (B,H,L,64)).
__global__ __launch_bounds__(256) void gemm_rope(
    const unsigned short* __restrict__ xb, const unsigned short* __restrict__ wt,
    const float* __restrict__ bias, const float* __restrict__ sin_t,
    const float* __restrict__ cos_t, unsigned short* __restrict__ q_ws,
    unsigned short* __restrict__ k_ws) {
  // union: K-loop uses first 16KB as As/Bs; epilogue reuses all 34.8KB
  __shared__ __align__(16) unsigned short smem[128 * 136];
  unsigned short* As = smem;          // 128*32 = 4096 ushorts (8KB)
  unsigned short* Bs = smem + 4096;   // 8KB
  const int tid = threadIdx.x;
  const int bx = blockIdx.x;
  const int tn = (bx % (NOUT / 128)) * 128;
  const int tm = (bx / (NOUT / 128)) * 128;
  const int wid = tid >> 6, lane = tid & 63;
  const int wm = (wid >> 1) * 64, wn = (wid & 1) * 64;
  const int lrow = lane & 15, lk = (lane >> 4) * 8;

  const int sr = tid >> 2;
  const int sc = (tid & 3) * 8;
  const unsigned short* a_src0 = xb + (size_t)(tm + sr) * DIM + sc;
  const unsigned short* a_src1 = xb + (size_t)(tm + 64 + sr) * DIM + sc;
  const unsigned short* b_src0 = wt + (size_t)(tn + sr) * DIM + sc;
  const unsigned short* b_src1 = wt + (size_t)(tn + 64 + sr) * DIM + sc;
  unsigned short* a_dst0 = &As[tid * 8];
  unsigned short* a_dst1 = &As[2048 + tid * 8];
  unsigned short* b_dst0 = &Bs[tid * 8];
  unsigned short* b_dst1 = &Bs[2048 + tid * 8];

  f32x4 acc[4][4] = {};  // [ai = n-frag][bi = m-frag]
  for (int k0 = 0; k0 < DIM; k0 += 32) {
    async16(a_src0 + k0, a_dst0);
    async16(a_src1 + k0, a_dst1);
    async16(b_src0 + k0, b_dst0);
    async16(b_src1 + k0, b_dst1);
    __syncthreads();
    bf16x8 nf[4], mf[4];
#pragma unroll
    for (int i = 0; i < 4; ++i) {
      nf[i] = *(const bf16x8*)&Bs[(wn + i * 16 + lrow) * 32 + lk];
      mf[i] = *(const bf16x8*)&As[(wm + i * 16 + lrow) * 32 + lk];
    }
#pragma unroll
    for (int ai = 0; ai < 4; ++ai)
#pragma unroll
      for (int bi = 0; bi < 4; ++bi)
        acc[ai][bi] = __builtin_amdgcn_mfma_f32_16x16x32_bf16(
            nf[ai], mf[bi], acc[ai][bi], 0, 0, 0);
    __syncthreads();
  }

  // ---- epilogue phase 1: bias + RoPE in regs, dump ushort4 into LDS[m][n] ----
#pragma unroll
  for (int ai = 0; ai < 4; ++ai) {
    const int nloc = wn + ai * 16 + (lane >> 4) * 4;  // 0..127, 4-aligned
    const int colb = tn + nloc;
    const int d0 = colb & 63;
    const float4 b4 = *(const float4*)&bias[colb];
#pragma unroll
    for (int bi = 0; bi < 4; ++bi) {
      const int mloc = wm + bi * 16 + lrow;           // 0..127
      const int pos = (tm + mloc) & (SEQ - 1);
      const float2 s01 = *(const float2*)&sin_t[pos * 32 + (d0 >> 1)];
      const float2 c01 = *(const float2*)&cos_t[pos * 32 + (d0 >> 1)];
      const float v0 = acc[ai][bi][0] + b4.x;
      const float v1 = acc[ai][bi][1] + b4.y;
      const float v2 = acc[ai][bi][2] + b4.z;
      const float v3 = acc[ai][bi][3] + b4.w;
      u16x4 pk;
      pk[0] = f2b(fmaf(v0, c01.x, -v1 * s01.x));
      pk[1] = f2b(fmaf(v1, c01.x,  v0 * s01.x));
      pk[2] = f2b(fmaf(v2, c01.y, -v3 * s01.y));
      pk[3] = f2b(fmaf(v3, c01.y,  v2 * s01.y));
      *(u16x4*)&smem[mloc * 136 + nloc] = pk;
    }
  }
  __syncthreads();

  // ---- epilogue phase 2: coalesced read-out; 1KB contiguous per wave ----
  const int bq = tm >> 9;          // batch (tile spans one b)
  const int pos0 = tm & (SEQ - 1);
  const int head = tn >> 7;        // tile spans one head (q cols 0-63, k 64-127)
  const size_t rowbase = ((size_t)(bq * HEADS + head) * SEQ + pos0);
  const int rr = tid >> 3;         // 0..31
  const int cc = tid & 7;          // 0..7 (16B chunks of a 128B row-half)
#pragma unroll
  for (int p = 0; p < 4; ++p) {
    const int r = p * 32 + rr;
    u16x8 vq = *(const u16x8*)&smem[r * 136 + cc * 8];
    u16x8 vk = *(const u16x8*)&smem[r * 136 + 64 + cc * 8];
    *(u16x8*)&q_ws[(rowbase + r) * 64 + cc * 8] = vq;
    *(u16x8*)&k_ws[(rowbase + r) * 64 + cc * 8] = vk;
  }
}

// -------- kernel 5: logits = q @ k^T per (b,h); mask + tril + scale --------
// Operand-swapped MFMA; LDS-staged epilogue -> 512B contiguous segments.
__global__ __launch_bounds__(256) void qk_kernel(
    const unsigned short* __restrict__ q_ws, const unsigned short* __restrict__ k_ws,
    const float* __restrict__ mask, float* __restrict__ out) {
  __shared__ __align__(16) float ot[128 * 132];  // 67.6 KB, 2 blocks/CU
  const int bx = blockIdx.x;
  const int bh = bx >> 4;
  const int t = bx & 15;
  const int tmm = (t >> 2) * 128, tnn = (t & 3) * 128;
  const int bidx = bh / HEADS;
  const int tid = threadIdx.x, wid = tid >> 6, lane = tid & 63;
  const int wm = (wid >> 1) * 64, wn = (wid & 1) * 64;
  const int lrow = lane & 15, lk = (lane >> 4) * 8;
  const unsigned short* Q = q_ws + ((size_t)bh << 15);  // 512*64
  const unsigned short* K = k_ws + ((size_t)bh << 15);

  bf16x8 kf[4][2], qf[4][2];
#pragma unroll
  for (int i = 0; i < 4; ++i) {
#pragma unroll
    for (int ks = 0; ks < 2; ++ks) {
      kf[i][ks] = *(const bf16x8*)&K[(size_t)(tnn + wn + i * 16 + lrow) * 64 + ks * 32 + lk];
      qf[i][ks] = *(const bf16x8*)&Q[(size_t)(tmm + wm + i * 16 + lrow) * 64 + ks * 32 + lk];
    }
  }
  f32x4 acc[4][4] = {};  // [ai = n][bi = m]
#pragma unroll
  for (int ai = 0; ai < 4; ++ai)
#pragma unroll
    for (int bi = 0; bi < 4; ++bi) {
      acc[ai][bi] = __builtin_amdgcn_mfma_f32_16x16x32_bf16(kf[ai][0], qf[bi][0], acc[ai][bi], 0, 0, 0);
      acc[ai][bi] = __builtin_amdgcn_mfma_f32_16x16x32_bf16(kf[ai][1], qf[bi][1], acc[ai][bi], 0, 0, 0);
    }

  // dump raw acc into LDS[mloc][nloc]
#pragma unroll
  for (int ai = 0; ai < 4; ++ai) {
    const int nloc = wn + ai * 16 + (lane >> 4) * 4;
#pragma unroll
    for (int bi = 0; bi < 4; ++bi) {
      const int mloc = wm + bi * 16 + lrow;
      *(f32x4*)&ot[mloc * 132 + nloc] = acc[ai][bi];
    }
  }
  __syncthreads();

  // coalesced read-out with mask/tril/scale: lanes 0-31 = one full 512B row
  float* obase = out + ((size_t)bh << 18);  // 512*512
  const float* mrow = mask + (size_t)bidx * SEQ;
  const int cc = tid & 31;         // 16B chunk within 512B row
  const int rr = tid >> 5;         // 0..7
  const int n0 = tnn + cc * 4;
  const f32x4 m3v = *(const f32x4*)&mrow[n0];
#pragma unroll
  for (int p = 0; p < 16; ++p) {
    const int r = p * 8 + rr;
    const int m = tmm + r;
    f32x4 v = *(const f32x4*)&ot[r * 132 + cc * 4];
    const float m2 = mrow[m];
    f32x4 o;
#pragma unroll
    for (int j = 0; j < 4; ++j) {
      float vv = v[j];
      vv = vv * m2 + (1.0f - m2) * (-NEGV);
      vv = vv * m3v[j] + (1.0f - m3v[j]) * (-NEGV);
      if (m > n0 + j) vv -= NEGV;
      o[j] = vv * 0.125f;
    }
    __builtin_nontemporal_store(o, (f32x4*)&obase[(size_t)m * 512 + n0]);
  }
}

extern "C" void kernel_launch(void* const* d_in, const int* in_sizes, int n_in,
                              void* d_out, int out_size, void* d_ws, size_t ws_size,
                              hipStream_t stream) {
  const float* x = (const float*)d_in[0];
  const float* mask = (const float*)d_in[1];
  const float* W = (const float*)d_in[2];
  const float* b = (const float*)d_in[3];
  float* out = (float*)d_out;

  char* ws = (char*)d_ws;
  float* sin_t = (float*)(ws + 0);                        //  64 KB
  float* cos_t = (float*)(ws + 65536);                    //  64 KB
  unsigned short* xb  = (unsigned short*)(ws + 131072);   //  24 MB
  unsigned short* wt  = (unsigned short*)(ws + 25296896); //  2.25 MB
  unsigned short* q_ws = (unsigned short*)(ws + 27656192); // 24 MB
  unsigned short* k_ws = (unsigned short*)(ws + 52822016); // 24 MB

  rope_table<<<dim3(64), dim3(256), 0, stream>>>(sin_t, cos_t);
  convert_x<<<dim3(MROWS * DIM / 4 / 256), dim3(256), 0, stream>>>(x, xb);
  transpose_w<<<dim3(NOUT / 32, DIM / 32), dim3(256), 0, stream>>>(W, wt);
  gemm_rope<<<dim3((MROWS / 128) * (NOUT / 128)), dim3(256), 0, stream>>>(
      xb, wt, b, sin_t, cos_t, q_ws, k_ws);
  qk_kernel<<<dim3(BATCH * HEADS * 16), dim3(256), 0, stream>>>(q_ws, k_ws, mask, out);
}

// Round 10
// 519.317 us; speedup vs baseline: 1.0823x; 1.0199x over previous
//
#include <hip/hip_runtime.h>
#include <hip/hip_bf16.h>

#define HEADS 12
#define HSIZE 64
#define BATCH 32
#define SEQ 512
#define DIM 768
#define NOUT 1536    // HEADS*HSIZE*2
#define MROWS 16384  // BATCH*SEQ
#define NEGV 1e12f

typedef __bf16 bf16x8 __attribute__((ext_vector_type(8)));
typedef float f32x4 __attribute__((ext_vector_type(4)));
typedef unsigned short u16x8 __attribute__((ext_vector_type(8)));
typedef unsigned short u16x4 __attribute__((ext_vector_type(4)));

__device__ __forceinline__ void async16(const void* g, void* l) {
  __builtin_amdgcn_global_load_lds(
      (const __attribute__((address_space(1))) void*)g,
      (__attribute__((address_space(3))) void*)l, 16, 0, 0);
}

__device__ __forceinline__ unsigned short f2b(float f) {
  union { __hip_bfloat16 h; unsigned short u; } cv;
  cv.h = __float2bfloat16(f);
  return cv.u;
}

// ---------------- kernel 1: RoPE sin/cos table (SEQ x 32) ----------------
__global__ void rope_table(float* __restrict__ sin_t, float* __restrict__ cos_t) {
  int idx = blockIdx.x * 256 + threadIdx.x;
  if (idx < SEQ * 32) {
    int pos = idx >> 5;
    int i = idx & 31;
    float freq = powf(10000.0f, -2.0f * (float)i / 64.0f);
    float ang = (float)pos * freq;
    sin_t[idx] = sinf(ang);
    cos_t[idx] = cosf(ang);
  }
}

// ---------------- kernel 2: x fp32 -> bf16, vectorized ----------------
__global__ void convert_x(const float* __restrict__ x, unsigned short* __restrict__ xb) {
  int idx = blockIdx.x * 256 + threadIdx.x;  // each handles 4 floats
  float4 v = ((const float4*)x)[idx];
  ushort4 o;
  o.x = f2b(v.x); o.y = f2b(v.y); o.z = f2b(v.z); o.w = f2b(v.w);
  ((ushort4*)xb)[idx] = o;
}

// ------------- kernel 3: W (DIM x NOUT) -> Wt (NOUT x DIM) bf16 -------------
__global__ void transpose_w(const float* __restrict__ W, unsigned short* __restrict__ Wt) {
  __shared__ unsigned short tile[32][33];
  int n0 = blockIdx.x * 32;
  int k0 = blockIdx.y * 32;
  int tx = threadIdx.x & 31, ty = threadIdx.x >> 5;  // 32 x 8
#pragma unroll
  for (int j = 0; j < 32; j += 8) {
    tile[ty + j][tx] = f2b(W[(size_t)(k0 + ty + j) * NOUT + n0 + tx]);
  }
  __syncthreads();
#pragma unroll
  for (int j = 0; j < 32; j += 8) {
    Wt[(size_t)(n0 + ty + j) * DIM + k0 + tx] = tile[tx][ty + j];
  }
}

// ---- kernel 4: proj = xb @ Wt^T (+bias, RoPE) -> q_ws/k_ws (B,H,L,64) bf16 ----
// 128x128 tile, BK=64 (12 iters, 32 MFMA per barrier-pair), 4 waves (2x2),
// operand-swapped MFMA (D rows = n -> RoPE pairs in-lane). LDS-staged epilogue.
__global__ __launch_bounds__(256) void gemm_rope(
    const unsigned short* __restrict__ xb, const unsigned short* __restrict__ wt,
    const float* __restrict__ bias, const float* __restrict__ sin_t,
    const float* __restrict__ cos_t, unsigned short* __restrict__ q_ws,
    unsigned short* __restrict__ k_ws) {
  // union: K-loop As(16KB)+Bs(16KB); epilogue [128][136] ushort (34.0KB)
  __shared__ __align__(16) unsigned short smem[128 * 136];
  unsigned short* As = smem;          // 128x64
  unsigned short* Bs = smem + 8192;   // 128x64
  const int tid = threadIdx.x;
  const int bx = blockIdx.x;
  const int tn = (bx % (NOUT / 128)) * 128;
  const int tm = (bx / (NOUT / 128)) * 128;
  const int wid = tid >> 6, lane = tid & 63;
  const int wm = (wid >> 1) * 64, wn = (wid & 1) * 64;
  const int lrow = lane & 15, lk = (lane >> 4) * 8;

  // staging map: 32 rows x 64 cols per issue; 4 issues each for A and B
  const int sr = tid >> 3;          // 0..31
  const int scb = (tid & 7) * 8;    // elem 0..56
  const unsigned short* a_src = xb + (size_t)(tm + sr) * DIM + scb;
  const unsigned short* b_src = wt + (size_t)(tn + sr) * DIM + scb;

  f32x4 acc[4][4] = {};  // [ai = n-frag][bi = m-frag]
  for (int kt = 0; kt < 12; ++kt) {
    const int k0 = kt * 64;
#pragma unroll
    for (int p = 0; p < 4; ++p) {
      async16(a_src + (size_t)(p * 32) * DIM + k0, &As[(p * 32 + sr) * 64 + scb]);
      async16(b_src + (size_t)(p * 32) * DIM + k0, &Bs[(p * 32 + sr) * 64 + scb]);
    }
    __syncthreads();  // compiler drains vmcnt before barrier
#pragma unroll
    for (int ks = 0; ks < 2; ++ks) {
      bf16x8 nf[4], mf[4];
#pragma unroll
      for (int i = 0; i < 4; ++i) {
        nf[i] = *(const bf16x8*)&Bs[(wn + i * 16 + lrow) * 64 + ks * 32 + lk];
        mf[i] = *(const bf16x8*)&As[(wm + i * 16 + lrow) * 64 + ks * 32 + lk];
      }
#pragma unroll
      for (int ai = 0; ai < 4; ++ai)
#pragma unroll
        for (int bi = 0; bi < 4; ++bi)
          acc[ai][bi] = __builtin_amdgcn_mfma_f32_16x16x32_bf16(
              nf[ai], mf[bi], acc[ai][bi], 0, 0, 0);
    }
    __syncthreads();
  }

  // ---- epilogue phase 1: bias + RoPE in regs, dump ushort4 into LDS[m][n] ----
#pragma unroll
  for (int ai = 0; ai < 4; ++ai) {
    const int nloc = wn + ai * 16 + (lane >> 4) * 4;  // 0..127, 4-aligned
    const int colb = tn + nloc;
    const int d0 = colb & 63;
    const float4 b4 = *(const float4*)&bias[colb];
#pragma unroll
    for (int bi = 0; bi < 4; ++bi) {
      const int mloc = wm + bi * 16 + lrow;           // 0..127
      const int pos = (tm + mloc) & (SEQ - 1);
      const float2 s01 = *(const float2*)&sin_t[pos * 32 + (d0 >> 1)];
      const float2 c01 = *(const float2*)&cos_t[pos * 32 + (d0 >> 1)];
      const float v0 = acc[ai][bi][0] + b4.x;
      const float v1 = acc[ai][bi][1] + b4.y;
      const float v2 = acc[ai][bi][2] + b4.z;
      const float v3 = acc[ai][bi][3] + b4.w;
      u16x4 pk;
      pk[0] = f2b(fmaf(v0, c01.x, -v1 * s01.x));
      pk[1] = f2b(fmaf(v1, c01.x,  v0 * s01.x));
      pk[2] = f2b(fmaf(v2, c01.y, -v3 * s01.y));
      pk[3] = f2b(fmaf(v3, c01.y,  v2 * s01.y));
      *(u16x4*)&smem[mloc * 136 + nloc] = pk;
    }
  }
  __syncthreads();

  // ---- epilogue phase 2: coalesced read-out; 1KB contiguous per wave ----
  const int bq = tm >> 9;          // batch (tile spans one b)
  const int pos0 = tm & (SEQ - 1);
  const int head = tn >> 7;        // tile spans one head (q cols 0-63, k 64-127)
  const size_t rowbase = ((size_t)(bq * HEADS + head) * SEQ + pos0);
  const int rr = tid >> 3;         // 0..31
  const int cc = tid & 7;          // 0..7 (16B chunks of a 128B row-half)
#pragma unroll
  for (int p = 0; p < 4; ++p) {
    const int r = p * 32 + rr;
    u16x8 vq = *(const u16x8*)&smem[r * 136 + cc * 8];
    u16x8 vk = *(const u16x8*)&smem[r * 136 + 64 + cc * 8];
    *(u16x8*)&q_ws[(rowbase + r) * 64 + cc * 8] = vq;
    *(u16x8*)&k_ws[(rowbase + r) * 64 + cc * 8] = vk;
  }
}

// -------- kernel 5: logits = q @ k^T per (b,h); mask + tril + scale --------
// One block per 128-row strip (grid B*H*4): Q frags loaded ONCE, 4 col-tiles.
// Waves split along m (wm = wid*32). Output staged per 64-col half in
// ot[128][68] (34.8KB -> 4 blocks/CU) then written as 256B-contiguous rows.
__global__ __launch_bounds__(256) void qk_kernel(
    const unsigned short* __restrict__ q_ws, const unsigned short* __restrict__ k_ws,
    const float* __restrict__ mask, float* __restrict__ out) {
  __shared__ __align__(16) float ot[128 * 68];  // 34816 B
  const int bx = blockIdx.x;
  const int bh = bx >> 2;
  const int tmm = (bx & 3) * 128;
  const int bidx = bh / HEADS;
  const int tid = threadIdx.x, wid = tid >> 6, lane = tid & 63;
  const int wm = wid * 32;
  const int lrow = lane & 15, lk = (lane >> 4) * 8;
  const unsigned short* Q = q_ws + ((size_t)bh << 15);  // 512*64
  const unsigned short* K = k_ws + ((size_t)bh << 15);

  bf16x8 qf[2][2];
#pragma unroll
  for (int mi = 0; mi < 2; ++mi)
#pragma unroll
    for (int ks = 0; ks < 2; ++ks)
      qf[mi][ks] = *(const bf16x8*)&Q[(size_t)(tmm + wm + mi * 16 + lrow) * 64 + ks * 32 + lk];

  float* obase = out + ((size_t)bh << 18);  // 512*512
  const float* mrow = mask + (size_t)bidx * SEQ;
  const int cc = tid & 15;   // 16B chunk within 256B (64-col) row half
  const int rr = tid >> 4;   // 0..15

  for (int t = 0; t < 4; ++t) {
    const int tnn = t * 128;
    bf16x8 kf[8][2];
#pragma unroll
    for (int ni = 0; ni < 8; ++ni)
#pragma unroll
      for (int ks = 0; ks < 2; ++ks)
        kf[ni][ks] = *(const bf16x8*)&K[(size_t)(tnn + ni * 16 + lrow) * 64 + ks * 32 + lk];

    f32x4 acc[8][2] = {};  // [ni][mi]
#pragma unroll
    for (int ks = 0; ks < 2; ++ks)
#pragma unroll
      for (int ni = 0; ni < 8; ++ni)
#pragma unroll
        for (int mi = 0; mi < 2; ++mi)
          acc[ni][mi] = __builtin_amdgcn_mfma_f32_16x16x32_bf16(
              kf[ni][ks], qf[mi][ks], acc[ni][mi], 0, 0, 0);

#pragma unroll
    for (int h = 0; h < 2; ++h) {
      __syncthreads();  // ot free (prev half's readers done)
#pragma unroll
      for (int ai = 0; ai < 4; ++ai) {
        const int nloc = ai * 16 + (lane >> 4) * 4;  // 0..63
#pragma unroll
        for (int mi = 0; mi < 2; ++mi) {
          const int mloc = wm + mi * 16 + lrow;
          *(f32x4*)&ot[mloc * 68 + nloc] = acc[h * 4 + ai][mi];
        }
      }
      __syncthreads();
      const int n0 = tnn + h * 64 + cc * 4;
      const f32x4 m3v = *(const f32x4*)&mrow[n0];
#pragma unroll
      for (int p = 0; p < 8; ++p) {
        const int r = p * 16 + rr;
        const int m = tmm + r;
        f32x4 v = *(const f32x4*)&ot[r * 68 + cc * 4];
        const float m2 = mrow[m];
        f32x4 o;
#pragma unroll
        for (int j = 0; j < 4; ++j) {
          float vv = v[j];
          vv = vv * m2 + (1.0f - m2) * (-NEGV);
          vv = vv * m3v[j] + (1.0f - m3v[j]) * (-NEGV);
          if (m > n0 + j) vv -= NEGV;
          o[j] = vv * 0.125f;
        }
        __builtin_nontemporal_store(o, (f32x4*)&obase[(size_t)m * 512 + n0]);
      }
    }
  }
}

extern "C" void kernel_launch(void* const* d_in, const int* in_sizes, int n_in,
                              void* d_out, int out_size, void* d_ws, size_t ws_size,
                              hipStream_t stream) {
  const float* x = (const float*)d_in[0];
  const float* mask = (const float*)d_in[1];
  const float* W = (const float*)d_in[2];
  const float* b = (const float*)d_in[3];
  float* out = (float*)d_out;

  char* ws = (char*)d_ws;
  float* sin_t = (float*)(ws + 0);                        //  64 KB
  float* cos_t = (float*)(ws + 65536);                    //  64 KB
  unsigned short* xb  = (unsigned short*)(ws + 131072);   //  24 MB
  unsigned short* wt  = (unsigned short*)(ws + 25296896); //  2.25 MB
  unsigned short* q_ws = (unsigned short*)(ws + 27656192); // 24 MB
  unsigned short* k_ws = (unsigned short*)(ws + 52822016); // 24 MB

  rope_table<<<dim3(64), dim3(256), 0, stream>>>(sin_t, cos_t);
  convert_x<<<dim3(MROWS * DIM / 4 / 256), dim3(256), 0, stream>>>(x, xb);
  transpose_w<<<dim3(NOUT / 32, DIM / 32), dim3(256), 0, stream>>>(W, wt);
  gemm_rope<<<dim3((MROWS / 128) * (NOUT / 128)), dim3(256), 0, stream>>>(
      xb, wt, b, sin_t, cos_t, q_ws, k_ws);
  qk_kernel<<<dim3(BATCH * HEADS * 4), dim3(256), 0, stream>>>(q_ws, k_ws, mask, out);
}

// Round 12
// 499.394 us; speedup vs baseline: 1.1255x; 1.0399x over previous
//
#include <hip/hip_runtime.h>
#include <hip/hip_bf16.h>

#define HEADS 12
#define HSIZE 64
#define BATCH 32
#define SEQ 512
#define DIM 768
#define NOUT 1536    // HEADS*HSIZE*2
#define MROWS 16384  // BATCH*SEQ
#define NEGV 1e12f

typedef __bf16 bf16x8 __attribute__((ext_vector_type(8)));
typedef float f32x4 __attribute__((ext_vector_type(4)));
typedef int i32x4 __attribute__((ext_vector_type(4)));
typedef int i32x8 __attribute__((ext_vector_type(8)));
typedef unsigned short u16x8 __attribute__((ext_vector_type(8)));
typedef unsigned short u16x4 __attribute__((ext_vector_type(4)));

__device__ __forceinline__ void async16(const void* g, void* l) {
  __builtin_amdgcn_global_load_lds(
      (const __attribute__((address_space(1))) void*)g,
      (__attribute__((address_space(3))) void*)l, 16, 0, 0);
}

__device__ __forceinline__ unsigned short f2b(float f) {
  union { __hip_bfloat16 h; unsigned short u; } cv;
  cv.h = __float2bfloat16(f);
  return cv.u;
}

// pack 4 floats -> 4 fp8 e4m3 bytes (OCP, gfx950 hw cvt)
__device__ __forceinline__ unsigned int pk4_fp8(float a, float b, float c, float d) {
  int v = 0;
  v = __builtin_amdgcn_cvt_pk_fp8_f32(a, b, v, false);
  v = __builtin_amdgcn_cvt_pk_fp8_f32(c, d, v, true);
  return (unsigned int)v;
}

// ---------------- kernel 1: RoPE sin/cos table (SEQ x 32) ----------------
__global__ void rope_table(float* __restrict__ sin_t, float* __restrict__ cos_t) {
  int idx = blockIdx.x * 256 + threadIdx.x;
  if (idx < SEQ * 32) {
    int pos = idx >> 5;
    int i = idx & 31;
    float freq = powf(10000.0f, -2.0f * (float)i / 64.0f);
    float ang = (float)pos * freq;
    sin_t[idx] = sinf(ang);
    cos_t[idx] = cosf(ang);
  }
}

// ---------------- kernel 2: x fp32 -> fp8 e4m3, vectorized ----------------
__global__ void convert_x(const float* __restrict__ x, unsigned int* __restrict__ xf8) {
  int idx = blockIdx.x * 256 + threadIdx.x;  // each handles 8 floats
  float4 v0 = ((const float4*)x)[idx * 2];
  float4 v1 = ((const float4*)x)[idx * 2 + 1];
  uint2 o;
  o.x = pk4_fp8(v0.x, v0.y, v0.z, v0.w);
  o.y = pk4_fp8(v1.x, v1.y, v1.z, v1.w);
  ((uint2*)xf8)[idx] = o;
}

// ------------- kernel 3: W (DIM x NOUT) fp32 -> Wt (NOUT x DIM) fp8 -------------
__global__ void transpose_w(const float* __restrict__ W, unsigned char* __restrict__ Wt) {
  __shared__ float tile[32][33];
  int n0 = blockIdx.x * 32;
  int k0 = blockIdx.y * 32;
  int tx = threadIdx.x & 31, ty = threadIdx.x >> 5;  // 32 x 8
#pragma unroll
  for (int j = 0; j < 32; j += 8) {
    tile[ty + j][tx] = W[(size_t)(k0 + ty + j) * NOUT + n0 + tx];
  }
  __syncthreads();
#pragma unroll
  for (int j = 0; j < 32; j += 8) {
    const int n = n0 + ty + j;
    Wt[(size_t)n * DIM + k0 + tx] =
        (unsigned char)(pk4_fp8(tile[tx][ty + j], 0.f, 0.f, 0.f) & 0xFF);
  }
}

// ---- kernel 4: proj = xf8 @ Wt^T (+bias, RoPE) -> q_ws/k_ws (B,H,L,64) bf16 ----
// MX-fp8 (scale=1.0) 16x16x128 MFMA, 128x128 tile, BK=128 (6 iters), 4 waves.
// T21 swizzle: linear LDS dest, XOR'd global source slot, XOR'd ds_read.
// Operand-swapped (D rows = n -> RoPE pairs in-lane). LDS-staged epilogue.
__global__ __launch_bounds__(256) void gemm_rope(
    const unsigned char* __restrict__ xf8, const unsigned char* __restrict__ wf8,
    const float* __restrict__ bias, const float* __restrict__ sin_t,
    const float* __restrict__ cos_t, unsigned short* __restrict__ q_ws,
    unsigned short* __restrict__ k_ws) {
  // K-loop: As 16KB + Bs 16KB; epilogue reuses as ushort[128*136] (34.8KB)
  __shared__ __align__(16) unsigned char smem[128 * 136 * 2];
  unsigned char* As = smem;           // 128 rows x 128 B
  unsigned char* Bs = smem + 16384;
  const int tid = threadIdx.x;
  const int bx = blockIdx.x;
  const int tn = (bx % (NOUT / 128)) * 128;
  const int tm = (bx / (NOUT / 128)) * 128;
  const int wid = tid >> 6, lane = tid & 63;
  const int wm = (wid >> 1) * 64, wn = (wid & 1) * 64;
  const int lrow = lane & 15;
  const int kc = lane >> 4;          // 0..3, 32-byte k-chunk

  // staging map: chunk p covers rows p*32+(tid>>3); phys slot s=tid&7 (16B),
  // source slot sigma = s ^ (row&7)  [row&7 = (tid>>3)&7]
  const int srow = tid >> 3;                       // 0..31
  const int sslot = (tid & 7) ^ (srow & 7);        // swizzled source slot
  const unsigned char* a_src = xf8 + (size_t)(tm + srow) * DIM + sslot * 16;
  const unsigned char* b_src = wf8 + (size_t)(tn + srow) * DIM + sslot * 16;
  unsigned char* a_dst = As + tid * 16;
  unsigned char* b_dst = Bs + tid * 16;

  f32x4 acc[4][4] = {};  // [ai = n-frag][bi = m-frag]
  for (int kt = 0; kt < 6; ++kt) {
    const int k0 = kt * 128;
#pragma unroll
    for (int p = 0; p < 4; ++p) {
      async16(a_src + (size_t)(p * 32) * DIM + k0, a_dst + p * 4096);
      async16(b_src + (size_t)(p * 32) * DIM + k0, b_dst + p * 4096);
    }
    __syncthreads();  // compiler drains vmcnt before barrier
    i32x8 nf[4], mf[4];
#pragma unroll
    for (int i = 0; i < 4; ++i) {
      {
        const int row = wn + i * 16 + lrow;
        const int sw = lrow & 7;
        union { i32x4 h[2]; i32x8 v; } u;
        u.h[0] = *(const i32x4*)&Bs[row * 128 + ((kc * 2) ^ sw) * 16];
        u.h[1] = *(const i32x4*)&Bs[row * 128 + ((kc * 2 + 1) ^ sw) * 16];
        nf[i] = u.v;
      }
      {
        const int row = wm + i * 16 + lrow;
        const int sw = lrow & 7;
        union { i32x4 h[2]; i32x8 v; } u;
        u.h[0] = *(const i32x4*)&As[row * 128 + ((kc * 2) ^ sw) * 16];
        u.h[1] = *(const i32x4*)&As[row * 128 + ((kc * 2 + 1) ^ sw) * 16];
        mf[i] = u.v;
      }
    }
#pragma unroll
    for (int ai = 0; ai < 4; ++ai)
#pragma unroll
      for (int bi = 0; bi < 4; ++bi)
        acc[ai][bi] = __builtin_amdgcn_mfma_scale_f32_16x16x128_f8f6f4(
            nf[ai], mf[bi], acc[ai][bi], 0, 0,
            0, 0x7F7F7F7F, 0, 0x7F7F7F7F);  // fp8/fp8, scales = 1.0
    __syncthreads();
  }

  // ---- epilogue phase 1: bias + RoPE in regs, dump ushort4 into LDS[m][n] ----
  unsigned short* osm = (unsigned short*)smem;  // [128][136]
#pragma unroll
  for (int ai = 0; ai < 4; ++ai) {
    const int nloc = wn + ai * 16 + (lane >> 4) * 4;  // 0..127, 4-aligned
    const int colb = tn + nloc;
    const int d0 = colb & 63;
    const float4 b4 = *(const float4*)&bias[colb];
#pragma unroll
    for (int bi = 0; bi < 4; ++bi) {
      const int mloc = wm + bi * 16 + lrow;           // 0..127
      const int pos = (tm + mloc) & (SEQ - 1);
      const float2 s01 = *(const float2*)&sin_t[pos * 32 + (d0 >> 1)];
      const float2 c01 = *(const float2*)&cos_t[pos * 32 + (d0 >> 1)];
      const float v0 = acc[ai][bi][0] + b4.x;
      const float v1 = acc[ai][bi][1] + b4.y;
      const float v2 = acc[ai][bi][2] + b4.z;
      const float v3 = acc[ai][bi][3] + b4.w;
      u16x4 pk;
      pk[0] = f2b(fmaf(v0, c01.x, -v1 * s01.x));
      pk[1] = f2b(fmaf(v1, c01.x,  v0 * s01.x));
      pk[2] = f2b(fmaf(v2, c01.y, -v3 * s01.y));
      pk[3] = f2b(fmaf(v3, c01.y,  v2 * s01.y));
      *(u16x4*)&osm[mloc * 136 + nloc] = pk;
    }
  }
  __syncthreads();

  // ---- epilogue phase 2: coalesced read-out; 1KB contiguous per wave ----
  const int bq = tm >> 9;          // batch (tile spans one b)
  const int pos0 = tm & (SEQ - 1);
  const int head = tn >> 7;        // tile spans one head (q cols 0-63, k 64-127)
  const size_t rowbase = ((size_t)(bq * HEADS + head) * SEQ + pos0);
  const int rr = tid >> 3;         // 0..31
  const int cc = tid & 7;          // 0..7 (16B chunks of a 128B row-half)
#pragma unroll
  for (int p = 0; p < 4; ++p) {
    const int r = p * 32 + rr;
    u16x8 vq = *(const u16x8*)&osm[r * 136 + cc * 8];
    u16x8 vk = *(const u16x8*)&osm[r * 136 + 64 + cc * 8];
    *(u16x8*)&q_ws[(rowbase + r) * 64 + cc * 8] = vq;
    *(u16x8*)&k_ws[(rowbase + r) * 64 + cc * 8] = vk;
  }
}

// -------- kernel 5: logits = q @ k^T per (b,h); mask + tril + scale --------
// One block per 128-row strip (grid B*H*4): Q frags loaded ONCE, 4 col-tiles.
// Waves split along m (wm = wid*32). Output staged per 64-col half in
// ot[128][68] (34.8KB -> 4 blocks/CU) then written as 256B-contiguous rows.
__global__ __launch_bounds__(256) void qk_kernel(
    const unsigned short* __restrict__ q_ws, const unsigned short* __restrict__ k_ws,
    const float* __restrict__ mask, float* __restrict__ out) {
  __shared__ __align__(16) float ot[128 * 68];  // 34816 B
  const int bx = blockIdx.x;
  const int bh = bx >> 2;
  const int tmm = (bx & 3) * 128;
  const int bidx = bh / HEADS;
  const int tid = threadIdx.x, wid = tid >> 6, lane = tid & 63;
  const int wm = wid * 32;
  const int lrow = lane & 15, lk = (lane >> 4) * 8;
  const unsigned short* Q = q_ws + ((size_t)bh << 15);  // 512*64
  const unsigned short* K = k_ws + ((size_t)bh << 15);

  bf16x8 qf[2][2];
#pragma unroll
  for (int mi = 0; mi < 2; ++mi)
#pragma unroll
    for (int ks = 0; ks < 2; ++ks)
      qf[mi][ks] = *(const bf16x8*)&Q[(size_t)(tmm + wm + mi * 16 + lrow) * 64 + ks * 32 + lk];

  float* obase = out + ((size_t)bh << 18);  // 512*512
  const float* mrow = mask + (size_t)bidx * SEQ;
  const int cc = tid & 15;   // 16B chunk within 256B (64-col) row half
  const int rr = tid >> 4;   // 0..15

  for (int t = 0; t < 4; ++t) {
    const int tnn = t * 128;
    bf16x8 kf[8][2];
#pragma unroll
    for (int ni = 0; ni < 8; ++ni)
#pragma unroll
      for (int ks = 0; ks < 2; ++ks)
        kf[ni][ks] = *(const bf16x8*)&K[(size_t)(tnn + ni * 16 + lrow) * 64 + ks * 32 + lk];

    f32x4 acc[8][2] = {};  // [ni][mi]
#pragma unroll
    for (int ks = 0; ks < 2; ++ks)
#pragma unroll
      for (int ni = 0; ni < 8; ++ni)
#pragma unroll
        for (int mi = 0; mi < 2; ++mi)
          acc[ni][mi] = __builtin_amdgcn_mfma_f32_16x16x32_bf16(
              kf[ni][ks], qf[mi][ks], acc[ni][mi], 0, 0, 0);

#pragma unroll
    for (int h = 0; h < 2; ++h) {
      __syncthreads();  // ot free (prev half's readers done)
#pragma unroll
      for (int ai = 0; ai < 4; ++ai) {
        const int nloc = ai * 16 + (lane >> 4) * 4;  // 0..63
#pragma unroll
        for (int mi = 0; mi < 2; ++mi) {
          const int mloc = wm + mi * 16 + lrow;
          *(f32x4*)&ot[mloc * 68 + nloc] = acc[h * 4 + ai][mi];
        }
      }
      __syncthreads();
      const int n0 = tnn + h * 64 + cc * 4;
      const f32x4 m3v = *(const f32x4*)&mrow[n0];
#pragma unroll
      for (int p = 0; p < 8; ++p) {
        const int r = p * 16 + rr;
        const int m = tmm + r;
        f32x4 v = *(const f32x4*)&ot[r * 68 + cc * 4];
        const float m2 = mrow[m];
        f32x4 o;
#pragma unroll
        for (int j = 0; j < 4; ++j) {
          float vv = v[j];
          vv = vv * m2 + (1.0f - m2) * (-NEGV);
          vv = vv * m3v[j] + (1.0f - m3v[j]) * (-NEGV);
          if (m > n0 + j) vv -= NEGV;
          o[j] = vv * 0.125f;
        }
        __builtin_nontemporal_store(o, (f32x4*)&obase[(size_t)m * 512 + n0]);
      }
    }
  }
}

extern "C" void kernel_launch(void* const* d_in, const int* in_sizes, int n_in,
                              void* d_out, int out_size, void* d_ws, size_t ws_size,
                              hipStream_t stream) {
  const float* x = (const float*)d_in[0];
  const float* mask = (const float*)d_in[1];
  const float* W = (const float*)d_in[2];
  const float* b = (const float*)d_in[3];
  float* out = (float*)d_out;

  char* ws = (char*)d_ws;
  float* sin_t = (float*)(ws + 0);                          //  64 KB
  float* cos_t = (float*)(ws + 65536);                      //  64 KB
  unsigned char* xf8 = (unsigned char*)(ws + 131072);       // 12.6 MB (16384x768)
  unsigned char* wf8 = (unsigned char*)(ws + 12713984);     // 1.18 MB (1536x768)
  unsigned short* q_ws = (unsigned short*)(ws + 13893632);  // 24 MB (32,12,512,64)
  unsigned short* k_ws = (unsigned short*)(ws + 39059456);  // 24 MB

  rope_table<<<dim3(64), dim3(256), 0, stream>>>(sin_t, cos_t);
  convert_x<<<dim3(MROWS * DIM / 8 / 256), dim3(256), 0, stream>>>(x, (unsigned int*)xf8);
  transpose_w<<<dim3(NOUT / 32, DIM / 32), dim3(256), 0, stream>>>(W, wf8);
  gemm_rope<<<dim3((MROWS / 128) * (NOUT / 128)), dim3(256), 0, stream>>>(
      xf8, wf8, b, sin_t, cos_t, q_ws, k_ws);
  qk_kernel<<<dim3(BATCH * HEADS * 4), dim3(256), 0, stream>>>(q_ws, k_ws, mask, out);
}